// Round 11
// baseline (572.903 us; speedup 1.0000x reference)
//
#include <hip/hip_runtime.h>
#include <stdint.h>

// DynamicQuantizedLinear on MI355X.
// d_in = {x: f32 [2048,4096], weight_q: int32 [11008,4096], scale: f32 [11008],
//         bias: f32 [11008]}, d_out = f32 [2048,11008].
//
// R9 lesson: prep_w (int32->f16 dequant prepass) was stuck at ~255us (~1.1TB/s)
// regardless of structure. Eliminated: the GEMM now consumes WQ int32 directly.
// B-tile is register-staged per K-step (issue loads early, convert fp16(wq*s)
// and ds_write late -> latency hides under the MFMA phase). B values are
// bit-identical to the reference's materialized weight_deq. A-path (X16 f16 via
// global_load_lds) and the m97 sync structure (one barrier/K-step) unchanged.
// Grid: bm-fastest (W-panel reuse, FETCH 1.01GB->342MB measured) + XCD chunking.

#define M_DIM 2048
#define N_DIM 11008
#define K_DIM 4096
#define BM 128
#define BN 128
#define BK 32
#define NKT (K_DIM / BK)

#define NXQ (M_DIM * K_DIM / 4)   // x quads: 2,097,152 = 8192 * 256

typedef _Float16 f16x4 __attribute__((ext_vector_type(4)));
typedef _Float16 f16x8 __attribute__((ext_vector_type(8)));
typedef float    f32x4 __attribute__((ext_vector_type(4)));

// ---------------- pass 1: downcast x to fp16 (exact) ----------------
__global__ __launch_bounds__(256)
void prep_x(const float* __restrict__ X, _Float16* __restrict__ X16)
{
  const int i = blockIdx.x * 256 + threadIdx.x;
  const float4 v = ((const float4*)X)[i];
  f16x4 o = { (_Float16)v.x, (_Float16)v.y, (_Float16)v.z, (_Float16)v.w };
  ((f16x4*)X16)[i] = o;
}

// ---------------- pass 2: fused dequant + f16 GEMM ----------------
// async global->LDS, 16B per lane. LDS dest = wave-uniform base + lane*16.
__device__ __forceinline__ void async_cp16(void* lds, const void* g) {
  auto l = (__attribute__((address_space(3))) uint32_t*)(uintptr_t)lds; // low 32b = LDS offset
  auto p = (const __attribute__((address_space(1))) uint32_t*)(uintptr_t)g;
  __builtin_amdgcn_global_load_lds(p, l, 16, 0, 0);
}

__global__ __launch_bounds__(256, 3)
void qlinear_gemm(const _Float16* __restrict__ A, const int* __restrict__ WQ,
                  const float* __restrict__ SC, const float* __restrict__ BI,
                  float* __restrict__ O)
{
  __shared__ __align__(16) _Float16 sA[2][BM * BK];   // 16 KB
  __shared__ __align__(16) _Float16 sB[2][BN * BK];   // 16 KB

  const int t    = threadIdx.x;
  const int lane = t & 63;
  const int wid  = t >> 6;
  const int wr   = wid >> 1;     // wave row (0..1): 64 M-rows each
  const int wc   = wid & 1;      // wave col (0..1): 64 N-cols each
  const int fr   = lane & 15;    // A/B fragment row; C col
  const int fq   = lane >> 4;    // k-group (0..3)

  // Grid swizzle: XCD-chunked (1376 = 8 * 172, exact) then bm-fastest so the
  // 16 blocks sharing one W panel run adjacently -> panel fetched ~once.
  const int wg = (blockIdx.x & 7) * 172 + (blockIdx.x >> 3);
  const int m0 = (wg & 15) * BM;   // bm = wg % 16 (fastest)
  const int n0 = (wg >> 4) * BN;   // bn = wg / 16 (0..85)

  // ---- A staging (global_load_lds, unchanged): chunk c = t -> row c>>2, quarter c&3
  const _Float16* gA0 = A + (size_t)(m0 + (t >> 2)) * K_DIM + (t & 3) * 8;
  const int wbase = t & 0xC0;                // wave-uniform chunk base
  _Float16* lA = &sA[0][0] + wbase * 8;      // chunk*16B = chunk*8 f16

  // ---- B staging (register path with fused dequant):
  // round r (0..3): row = 32*r + (t>>3), k-chunk = (t&7)*4 int32 (16B load).
  const int brow = t >> 3;                   // 0..31
  const int bkq  = t & 7;                    // 0..7
  const int* gB = WQ + (size_t)(n0 + brow) * K_DIM + bkq * 4;
  float s[4];
#pragma unroll
  for (int r = 0; r < 4; ++r) s[r] = SC[n0 + 32 * r + brow];  // hoisted scales
  _Float16* lBw = &sB[0][0] + brow * BK + bkq * 4;            // + r*32*BK, + buf*BM*BK

  f32x4 acc[4][4] = {};

#define STAGE_A(buf, kt) do {                                                  \
    const int ko_ = (kt) * BK;                                                 \
    async_cp16((void*)(lA + (buf) * (BM * BK)),        gA0 + ko_);             \
    async_cp16((void*)(lA + (buf) * (BM * BK) + 2048), gA0 + (size_t)64 * K_DIM + ko_); \
  } while (0)

  // prologue: tile 0
  STAGE_A(0, 0);
  {
    int4 w0[4];
#pragma unroll
    for (int r = 0; r < 4; ++r)
      w0[r] = *(const int4*)(gB + (size_t)32 * r * K_DIM);
#pragma unroll
    for (int r = 0; r < 4; ++r) {
      f16x4 o = { (_Float16)(w0[r].x * s[r]), (_Float16)(w0[r].y * s[r]),
                  (_Float16)(w0[r].z * s[r]), (_Float16)(w0[r].w * s[r]) };
      *(f16x4*)(lBw + r * 32 * BK) = o;      // ds_write_b64, conflict-free
    }
  }
  __syncthreads();   // tile 0 ready (A DMA drained, B writes visible)

  for (int kt = 0; kt < NKT; ++kt) {
    const int cur = kt & 1;
    const bool pf = (kt + 1 < NKT);

    int4 wnx[4];
    if (pf) {
      STAGE_A(cur ^ 1, kt + 1);              // async A prefetch
#pragma unroll
      for (int r = 0; r < 4; ++r)            // issue B loads EARLY
        wnx[r] = *(const int4*)(gB + (kt + 1) * BK + (size_t)32 * r * K_DIM);
    }

    // compute current tile
    const _Float16* aB = &sA[cur][0] + (wr * 64 + fr) * BK + fq * 8;
    const _Float16* bB = &sB[cur][0] + (wc * 64 + fr) * BK + fq * 8;

    f16x8 af[4], bf[4];
#pragma unroll
    for (int i = 0; i < 4; ++i) af[i] = *(const f16x8*)(aB + i * 16 * BK); // ds_read_b128
#pragma unroll
    for (int i = 0; i < 4; ++i) bf[i] = *(const f16x8*)(bB + i * 16 * BK);

#pragma unroll
    for (int mi = 0; mi < 4; ++mi)
#pragma unroll
      for (int ni = 0; ni < 4; ++ni)
        acc[mi][ni] = __builtin_amdgcn_mfma_f32_16x16x32_f16(af[mi], bf[ni], acc[mi][ni], 0, 0, 0);

    if (pf) {                                // convert + write LATE (loads landed
#pragma unroll                               // during the MFMA phase)
      for (int r = 0; r < 4; ++r) {
        f16x4 o = { (_Float16)(wnx[r].x * s[r]), (_Float16)(wnx[r].y * s[r]),
                    (_Float16)(wnx[r].z * s[r]), (_Float16)(wnx[r].w * s[r]) };
        *(f16x4*)(lBw + (cur ^ 1) * (BM * BK) + r * 32 * BK) = o;
      }
    }
    __syncthreads();  // publishes next tile (A vmcnt + B lgkm drained)
  }

  // epilogue: C/D layout col=lane&15, row=(lane>>4)*4+j.
  // Match reference rounding order: fp16(dot), then + bias in fp16, store f32.
  const int om = m0 + wr * 64;
  const int on = n0 + wc * 64;
#pragma unroll
  for (int ni = 0; ni < 4; ++ni) {
    const int n = on + ni * 16 + fr;
    const float b = BI[n];
#pragma unroll
    for (int mi = 0; mi < 4; ++mi) {
      const int m = om + mi * 16 + fq * 4;
#pragma unroll
      for (int j = 0; j < 4; ++j) {
        const _Float16 h = (_Float16)acc[mi][ni][j];        // fp16(dot)
        const _Float16 r = (_Float16)((float)h + b);        // fp16(h + bias)
        O[(size_t)(m + j) * N_DIM + n] = (float)r;
      }
    }
  }
#undef STAGE_A
}

extern "C" void kernel_launch(void* const* d_in, const int* in_sizes, int n_in,
                              void* d_out, int out_size, void* d_ws, size_t ws_size,
                              hipStream_t stream) {
  const float* x  = (const float*)d_in[0];
  const int*   wq = (const int*)d_in[1];
  const float* sc = (const float*)d_in[2];
  const float* bi = (const float*)d_in[3];
  float* out = (float*)d_out;

  _Float16* x16 = (_Float16*)d_ws;                    // 16,777,216 B
  if (ws_size < (size_t)M_DIM * K_DIM * 2) return;    // leave output poisoned

  prep_x<<<dim3(NXQ / 256), dim3(256), 0, stream>>>(x, x16);   // 8192 blocks

  dim3 grid((M_DIM / BM) * (N_DIM / BN));   // 16 * 86 = 1376 blocks
  qlinear_gemm<<<grid, dim3(256), 0, stream>>>(x16, wq, sc, bi, out);
}